// Round 1
// baseline (432.243 us; speedup 1.0000x reference)
//
#include <hip/hip_runtime.h>
#include <hip/hip_bf16.h>
#include <stdint.h>

#define B_ 2
#define S_ 2048
#define H_ 1024
#define F_ 4096
#define E_ 8
#define KTOP_ 2
#define NTOK (B_*S_)          // 4096
#define NPAIR (KTOP_*NTOK)    // 8192
#define NPAIR_PAD (NPAIR+128)

// ---- workspace layout (bytes) ----
static const size_t WS_XG   = 131072;                                // lists/meta before this
static const size_t SZ_XG   = (size_t)NPAIR_PAD * H_ * 2;            // 17,039,360
static const size_t WS_W1T  = WS_XG + SZ_XG;
static const size_t SZ_W1T  = (size_t)E_ * F_ * H_ * 2;              // 67,108,864
static const size_t WS_W2T  = WS_W1T + SZ_W1T;
static const size_t SZ_W2T  = (size_t)E_ * H_ * F_ * 2;              // 67,108,864
static const size_t WS_HBUF = WS_W2T + SZ_W2T;
static const size_t SZ_HBUF = (size_t)NPAIR_PAD * F_ * 2;            // 68,157,440
static const size_t WS_YBUF = WS_HBUF + SZ_HBUF;
static const size_t SZ_YBUF = (size_t)NPAIR * H_ * 4;                // 33,554,432

typedef __attribute__((ext_vector_type(8))) short bf16x8;
typedef __attribute__((ext_vector_type(4))) float f32x4;

__device__ __forceinline__ unsigned short f2bf(float f) {
  unsigned int u = __float_as_uint(f);
  u += 0x7fffu + ((u >> 16) & 1u);   // round-to-nearest-even
  return (unsigned short)(u >> 16);
}

__device__ __forceinline__ void load_lds16(const void* g, void* l) {
  __builtin_amdgcn_global_load_lds(
      (const __attribute__((address_space(1))) unsigned int*)g,
      (__attribute__((address_space(3))) unsigned int*)l, 16, 0, 0);
}

// meta ints: [0..7]=counts [8..15]=fill [16..24]=offs [25]=ntiles [32..111]=desc
__global__ void k_init(int* meta) {
  if (threadIdx.x < 32) meta[threadIdx.x] = 0;
}

__global__ void k_count(const int* __restrict__ sel, int* meta) {
  int i = blockIdx.x * 256 + threadIdx.x;
  if (i < NPAIR) atomicAdd(&meta[sel[i]], 1);
}

__global__ void k_scan(int* meta) {
  if (threadIdx.x == 0) {
    int acc = 0, t = 0;
    for (int e = 0; e < E_; e++) {
      meta[16 + e] = acc;
      int c = meta[e];
      for (int r0 = 0; r0 < c; r0 += 128) meta[32 + (t++)] = (e << 13) | r0;
      acc += c;
    }
    meta[24] = acc;
    meta[25] = t;
  }
}

__global__ void k_fill(const int* __restrict__ sel, const float* __restrict__ probs,
                       int* meta, int* __restrict__ tok, int* __restrict__ slot,
                       float* __restrict__ prob) {
  int i = blockIdx.x * 256 + threadIdx.x;
  if (i < NPAIR) {
    int e = sel[i];
    int pos = meta[16 + e] + atomicAdd(&meta[8 + e], 1);
    tok[pos]  = i & (NTOK - 1);   // i = k*NTOK + token
    slot[pos] = i;
    prob[pos] = probs[i];
  }
}

__global__ void k_gather(const float* __restrict__ x, const int* __restrict__ tok,
                         unsigned short* __restrict__ Xg) {
  int p = blockIdx.x, t = threadIdx.x;
  int token = tok[p];
  float4 v = ((const float4*)(x + (size_t)token * H_))[t];
  ushort4 o;
  o.x = f2bf(v.x); o.y = f2bf(v.y); o.z = f2bf(v.z); o.w = f2bf(v.w);
  ((ushort4*)(Xg + (size_t)p * H_))[t] = o;
}

// src [E][R][C] f32 -> dst [E][C][R] bf16
__global__ void k_transpose(const float* __restrict__ src, unsigned short* __restrict__ dst,
                            int R, int C) {
  __shared__ float tile[32][33];
  int e = blockIdx.z;
  size_t c0 = (size_t)blockIdx.x * 32, r0 = (size_t)blockIdx.y * 32;
  int tx = threadIdx.x & 31, ty = threadIdx.x >> 5;
  const float* s = src + ((size_t)e * R + r0) * C + c0;
#pragma unroll
  for (int i = 0; i < 4; i++) tile[ty + 8 * i][tx] = s[(size_t)(ty + 8 * i) * C + tx];
  __syncthreads();
  unsigned short* d = dst + ((size_t)e * C + c0) * R + r0;
#pragma unroll
  for (int i = 0; i < 4; i++) d[(size_t)(ty + 8 * i) * R + tx] = f2bf(tile[tx][ty + 8 * i]);
}

// Grouped GEMM: C[M=pairs, N] = A[M,K] * Wt[N,K]^T ; tiles 128x128, BK=64, 4 waves.
// EP==0: Hbuf = gelu(acc + b1)  (bf16);  EP==1: ybuf[slot] = (acc + b2)*prob (f32)
template <int K, int EP>
__global__ __launch_bounds__(256, 2) void k_gemm(
    const short* __restrict__ Aall, const short* __restrict__ Wt,
    const float* __restrict__ bias, const int* __restrict__ meta,
    unsigned short* __restrict__ Hbuf, float* __restrict__ ybuf,
    const int* __restrict__ slot, const float* __restrict__ prob) {
  int tile = blockIdx.y;
  if (tile >= meta[25]) return;
  int d  = meta[32 + tile];
  int e  = d >> 13, r0 = d & 8191;
  int ne = meta[e];
  int p0 = meta[16 + e] + r0;
  int n0 = blockIdx.x * 128;
  const int NFULL = (EP == 0) ? F_ : H_;
  const short* A0 = Aall + (size_t)p0 * K;
  const short* B0 = Wt + ((size_t)e * NFULL + n0) * K;

  __shared__ short As[128 * 64];
  __shared__ short Bs[128 * 64];
  int t = threadIdx.x, lane = t & 63, wid = t >> 6;
  int wr = wid >> 1, wc = wid & 1, g = lane >> 4, l15 = lane & 15;
  f32x4 acc[4][4] = {};

  for (int k0 = 0; k0 < K; k0 += 64) {
#pragma unroll
    for (int c = 0; c < 4; c++) {
      int off = c * 4096 + wid * 1024 + lane * 16;  // LDS byte offset, = uniform + lane*16
      int row = off >> 7, inb = off & 127;
      int sinb = inb ^ ((row & 7) << 4);            // inverse-swizzled source (involution)
      load_lds16((const char*)A0 + ((size_t)row * K + k0) * 2 + sinb, (char*)As + off);
      load_lds16((const char*)B0 + ((size_t)row * K + k0) * 2 + sinb, (char*)Bs + off);
    }
    __syncthreads();
#pragma unroll
    for (int kk = 0; kk < 2; kk++) {
      bf16x8 af[4], bfr[4];
#pragma unroll
      for (int m = 0; m < 4; m++) {
        int row = wr * 64 + m * 16 + l15;
        af[m] = *(const bf16x8*)((const char*)As + row * 128 +
                                 ((kk * 64 + g * 16) ^ ((row & 7) << 4)));
      }
#pragma unroll
      for (int n = 0; n < 4; n++) {
        int row = wc * 64 + n * 16 + l15;
        bfr[n] = *(const bf16x8*)((const char*)Bs + row * 128 +
                                  ((kk * 64 + g * 16) ^ ((row & 7) << 4)));
      }
#pragma unroll
      for (int m = 0; m < 4; m++)
#pragma unroll
        for (int n = 0; n < 4; n++)
          acc[m][n] = __builtin_amdgcn_mfma_f32_16x16x32_bf16(af[m], bfr[n], acc[m][n], 0, 0, 0);
    }
    __syncthreads();
  }

  if (EP == 0) {
#pragma unroll
    for (int n = 0; n < 4; n++) {
      int col = n0 + wc * 64 + n * 16 + l15;
      float bv = bias[e * F_ + col];
#pragma unroll
      for (int m = 0; m < 4; m++) {
        int rbase = wr * 64 + m * 16 + g * 4;
#pragma unroll
        for (int r = 0; r < 4; r++) {
          int row = rbase + r;
          if (r0 + row < ne) {
            float x = acc[m][n][r] + bv;
            float y = 0.7978845608f * x * (1.f + 0.044715f * x * x);
            y = fminf(y, 20.f);
            float u = __expf(2.f * y);
            float th = (u - 1.f) / (u + 1.f);
            Hbuf[(size_t)(p0 + row) * F_ + col] = f2bf(0.5f * x * (1.f + th));
          }
        }
      }
    }
  } else {
#pragma unroll
    for (int n = 0; n < 4; n++) {
      int col = n0 + wc * 64 + n * 16 + l15;
      float bv = bias[e * H_ + col];
#pragma unroll
      for (int m = 0; m < 4; m++) {
        int rbase = wr * 64 + m * 16 + g * 4;
#pragma unroll
        for (int r = 0; r < 4; r++) {
          int row = rbase + r;
          if (r0 + row < ne) {
            int p = p0 + row;
            ybuf[(size_t)slot[p] * H_ + col] = (acc[m][n][r] + bv) * prob[p];
          }
        }
      }
    }
  }
}

__global__ void k_combine(const float* __restrict__ yb, float* __restrict__ out) {
  size_t i = (size_t)blockIdx.x * 256 + threadIdx.x;
  float4 a = ((const float4*)yb)[i];
  float4 b = ((const float4*)(yb + (size_t)NTOK * H_))[i];
  float4 o;
  o.x = a.x + b.x; o.y = a.y + b.y; o.z = a.z + b.z; o.w = a.w + b.w;
  ((float4*)out)[i] = o;
}

extern "C" void kernel_launch(void* const* d_in, const int* in_sizes, int n_in,
                              void* d_out, int out_size, void* d_ws, size_t ws_size,
                              hipStream_t stream) {
  const float* x     = (const float*)d_in[0];
  const float* probs = (const float*)d_in[1];
  const int*   sel   = (const int*)d_in[2];
  const float* w1    = (const float*)d_in[3];
  const float* b1    = (const float*)d_in[4];
  const float* w2    = (const float*)d_in[5];
  const float* b2    = (const float*)d_in[6];
  float* out = (float*)d_out;

  char* W = (char*)d_ws;
  int*   meta = (int*)W;
  int*   tok  = (int*)(W + 4096);
  int*   slot = (int*)(W + 36864);
  float* prob = (float*)(W + 69632);
  unsigned short* Xg  = (unsigned short*)(W + WS_XG);
  short* w1t = (short*)(W + WS_W1T);
  short* w2t = (short*)(W + WS_W2T);
  unsigned short* Hb  = (unsigned short*)(W + WS_HBUF);
  float* yb  = (float*)(W + WS_YBUF);

  k_init<<<1, 256, 0, stream>>>(meta);
  k_count<<<NPAIR / 256, 256, 0, stream>>>(sel, meta);
  k_scan<<<1, 64, 0, stream>>>(meta);
  k_fill<<<NPAIR / 256, 256, 0, stream>>>(sel, probs, meta, tok, slot, prob);
  k_gather<<<NPAIR, 256, 0, stream>>>(x, tok, Xg);
  k_transpose<<<dim3(F_ / 32, H_ / 32, E_), 256, 0, stream>>>(w1, (unsigned short*)w1t, H_, F_);
  k_transpose<<<dim3(H_ / 32, F_ / 32, E_), 256, 0, stream>>>(w2, (unsigned short*)w2t, F_, H_);
  k_gemm<H_, 0><<<dim3(F_ / 128, 72), 256, 0, stream>>>(
      (const short*)Xg, w1t, b1, meta, Hb, yb, slot, prob);
  k_gemm<F_, 1><<<dim3(H_ / 128, 72), 256, 0, stream>>>(
      (const short*)Hb, w2t, b2, meta, Hb, yb, slot, prob);
  k_combine<<<(NTOK * H_ / 4) / 256, 256, 0, stream>>>(yb, out);
}